// Round 5
// baseline (314.575 us; speedup 1.0000x reference)
//
#include <hip/hip_runtime.h>
#include <hip/hip_bf16.h>

using bf16 = __hip_bfloat16;
typedef __attribute__((ext_vector_type(8))) short short8;     // 8 bf16 MFMA a/b frag
typedef __attribute__((ext_vector_type(16))) float floatx16;  // 32x32 MFMA c/d frag

#define NEG_INF (-__builtin_huge_valf())

// async global->LDS, 16B per lane. LDS dest is wave-uniform base + lane*16.
__device__ __forceinline__ void gld_lds16(const void* g, void* l) {
  __builtin_amdgcn_global_load_lds(
      (const __attribute__((address_space(1))) unsigned int*)g,
      (__attribute__((address_space(3))) unsigned int*)l, 16, 0, 0);
}

__device__ __forceinline__ void cvt8(const float4& a, const float4& b, bf16* t) {
  t[0] = __float2bfloat16(a.x); t[1] = __float2bfloat16(a.y);
  t[2] = __float2bfloat16(a.z); t[3] = __float2bfloat16(a.w);
  t[4] = __float2bfloat16(b.x); t[5] = __float2bfloat16(b.y);
  t[6] = __float2bfloat16(b.z); t[7] = __float2bfloat16(b.w);
}

// ---- algebra: logits = [X·M·Y^T + u·1^T + 1·v^T + c]/64,
//      M = qw^T·kw,  u = X·(qw^T kb),  v = Y·(kw^T qb),  c = qb·kb.

// ---------------- prep (fused, 80 blocks)  [verified R4] -------------------
//   blocks 0-63 : Mt[n,k] = M[k,n] = sum_i qw[i,k]*kw[i,n]  (bf16, 64x64 tile)
//   blocks 64-79: w1 = qw^T·kb (8) / w2 = kw^T·qb (8); block 64 adds c = qb·kb
__global__ __launch_bounds__(256) void prep(const float* __restrict__ qw,
                                            const float* __restrict__ kw,
                                            const float* __restrict__ qb,
                                            const float* __restrict__ kb,
                                            bf16* __restrict__ mtp,
                                            float* __restrict__ w1,
                                            float* __restrict__ w2,
                                            float* __restrict__ cks) {
  __shared__ float pool[2][2][8][64];   // 8 KiB, reused by both halves
  const int bid = blockIdx.x;
  const int tid = threadIdx.x;

  if (bid < 64) {
    float (*skw)[8][64] = pool[0];      // kw[i, n0+..]
    float (*sqw)[8][64] = pool[1];      // qw[i, k0+..]
    const int n0 = (bid >> 3) * 64, k0 = (bid & 7) * 64;
    const int tr = tid >> 4, tc = tid & 15;
    const int sr = tid >> 5, sc = (tid & 31) * 2;
    float acc[4][4];
    #pragma unroll
    for (int x = 0; x < 4; ++x)
      #pragma unroll
      for (int y = 0; y < 4; ++y) acc[x][y] = 0.f;

    auto stage = [&](int buf, int i0) {
      float2 kv = *(const float2*)&kw[(size_t)(i0 + sr) * 512 + n0 + sc];
      float2 qv = *(const float2*)&qw[(size_t)(i0 + sr) * 512 + k0 + sc];
      skw[buf][sr][sc] = kv.x; skw[buf][sr][sc + 1] = kv.y;
      sqw[buf][sr][sc] = qv.x; sqw[buf][sr][sc + 1] = qv.y;
    };
    stage(0, 0);
    __syncthreads();
    for (int cb = 0; cb < 64; ++cb) {
      if (cb < 63) stage((cb + 1) & 1, (cb + 1) * 8);
      const int buf = cb & 1;
      #pragma unroll
      for (int ii = 0; ii < 8; ++ii) {
        float av[4], bv[4];
        #pragma unroll
        for (int x = 0; x < 4; ++x) av[x] = skw[buf][ii][tr * 4 + x];
        #pragma unroll
        for (int y = 0; y < 4; ++y) bv[y] = sqw[buf][ii][tc * 4 + y];
        #pragma unroll
        for (int x = 0; x < 4; ++x)
          #pragma unroll
          for (int y = 0; y < 4; ++y) acc[x][y] += av[x] * bv[y];
      }
      __syncthreads();
    }
    #pragma unroll
    for (int x = 0; x < 4; ++x)
      #pragma unroll
      for (int y = 0; y < 4; ++y)
        mtp[(size_t)(n0 + tr * 4 + x) * 512 + k0 + tc * 4 + y] =
            __float2bfloat16(acc[x][y]);
  } else {
    const int bid2 = bid - 64;          // 0..15
    const bool isW1 = bid2 < 8;
    const float* src = isW1 ? qw : kw;
    const float* vec = isW1 ? kb : qb;
    float* outp      = isW1 ? w1 : w2;
    const int j = ((bid2 & 7) << 6) | (tid & 63);
    const int q = tid >> 6;             // wave id, i-quarter
    float p = 0.f;
    #pragma unroll 8
    for (int i = q * 128; i < q * 128 + 128; ++i)
      p += src[(size_t)i * 512 + j] * vec[i];
    float* red = &pool[0][0][0][0];
    red[tid] = p;
    __syncthreads();
    if (tid < 64)
      outp[j] = red[tid] + red[tid + 64] + red[tid + 128] + red[tid + 192];
    if (bid2 == 0) {                    // block-uniform branch
      __syncthreads();
      red[tid] = qb[tid] * kb[tid] + qb[tid + 256] * kb[tid + 256];
      __syncthreads();
      for (int s = 128; s > 0; s >>= 1) {
        if (tid < s) red[tid] += red[tid + s];
        __syncthreads();
      }
      if (tid == 0) *cks = red[0];
    }
  }
}

// 32x32x16 MFMA block: wave covers 64x64 as 2x2 of 32x32 tiles.
// A/B operand: m|n = lane&31, k = (lane>>5)*8 + j  (row-major [rows][32] LDS tile)
// C/D: col = lane&31, row = (reg&3) + 8*(reg>>2) + 4*(lane>>5)   [m74/m101]
__device__ __forceinline__ void mfma_tile32(const bf16* sAh, const bf16* sBh,
                                            int wm, int wn, int lane,
                                            floatx16 acc[2][2]) {
  const int fm = lane & 31;
  const int fk = (lane >> 5) * 8;
  #pragma unroll
  for (int ks = 0; ks < 2; ++ks) {
    short8 a0 = *(const short8*)(sAh + (wm +  0 + fm) * 32 + ks * 16 + fk);
    short8 a1 = *(const short8*)(sAh + (wm + 32 + fm) * 32 + ks * 16 + fk);
    short8 b0 = *(const short8*)(sBh + (wn +  0 + fm) * 32 + ks * 16 + fk);
    short8 b1 = *(const short8*)(sBh + (wn + 32 + fm) * 32 + ks * 16 + fk);
    acc[0][0] = __builtin_amdgcn_mfma_f32_32x32x16_bf16(a0, b0, acc[0][0], 0, 0, 0);
    acc[0][1] = __builtin_amdgcn_mfma_f32_32x32x16_bf16(a0, b1, acc[0][1], 0, 0, 0);
    acc[1][0] = __builtin_amdgcn_mfma_f32_32x32x16_bf16(a1, b0, acc[1][0], 0, 0, 0);
    acc[1][1] = __builtin_amdgcn_mfma_f32_32x32x16_bf16(a1, b1, acc[1][1], 0, 0, 0);
  }
}

// ---------------- proj_z: Z_bf16 = cvt(X_f32)·Mt^T, fused u = X·w1 + c -----
// R0 proj_fused structure (fp32 A through registers), grid (64,4), 256 thr.
__global__ __launch_bounds__(256) void proj_z(const float* __restrict__ X,
                                              const bf16* __restrict__ Mt,
                                              const float* __restrict__ w1,
                                              const float* __restrict__ cks,
                                              bf16* __restrict__ Z,
                                              float* __restrict__ u) {
  __shared__ bf16 sA[2][128 * 32];
  __shared__ bf16 sB[2][128 * 32];
  const int m0 = blockIdx.x * 128;
  const int n0 = blockIdx.y * 128;
  const bool doU = (blockIdx.y == 0);

  const int tid  = threadIdx.x;
  const int lane = tid & 63;
  const int w    = tid >> 6;
  const int wm   = (w >> 1) * 64;
  const int wn   = (w & 1) * 64;
  const int st_row = lane >> 2;
  const int st_col = (lane & 3) * 8;

  floatx16 acc[2][2];
  #pragma unroll
  for (int mi = 0; mi < 2; ++mi)
    #pragma unroll
    for (int ni = 0; ni < 2; ++ni)
      #pragma unroll
      for (int r = 0; r < 16; ++r)
        acc[mi][ni][r] = 0.f;

  float pu[2] = {0.f, 0.f};             // u-partials for this thread's 2 rows

  for (int kt = 0; kt < 512; kt += 64) {
    // B-side: async DMA both 128x32 sub-tiles of Mt
    #pragma unroll
    for (int h = 0; h < 2; ++h)
      #pragma unroll
      for (int j = 0; j < 2; ++j) {
        const int r = (w << 5) + (j << 4);
        gld_lds16(Mt + (size_t)(n0 + r + st_row) * 512 + kt + h * 32 + st_col,
                  &sB[h][r * 32]);
      }
    // A-side: fp32 load, cvt, ds_write; fused u-dot in registers
    #pragma unroll
    for (int h = 0; h < 2; ++h)
      #pragma unroll
      for (int j = 0; j < 2; ++j) {
        const int row = (w << 5) + (j << 4) + st_row;
        const float* ga = X + (size_t)(m0 + row) * 512 + kt + h * 32 + st_col;
        float4 a0 = *(const float4*)ga;
        float4 a1 = *(const float4*)(ga + 4);
        bf16 ta[8];
        cvt8(a0, a1, ta);
        *(short8*)(&sA[h][row * 32 + st_col]) = *(short8*)ta;
        if (doU) {
          const float* wv = w1 + kt + h * 32 + st_col;
          float4 wa = *(const float4*)wv;
          float4 wb = *(const float4*)(wv + 4);
          pu[j] += a0.x * wa.x + a0.y * wa.y + a0.z * wa.z + a0.w * wa.w +
                   a1.x * wb.x + a1.y * wb.y + a1.z * wb.z + a1.w * wb.w;
        }
      }
    __syncthreads();

    #pragma unroll
    for (int h = 0; h < 2; ++h)
      mfma_tile32(sA[h], sB[h], wm, wn, lane, acc);
    __syncthreads();
  }

  if (doU) {
    const float c = *cks;
    #pragma unroll
    for (int j = 0; j < 2; ++j) {
      float p = pu[j];
      p += __shfl_xor(p, 1, 64);
      p += __shfl_xor(p, 2, 64);
      if ((lane & 3) == 0)
        u[m0 + (w << 5) + (j << 4) + st_row] = p + c;
    }
  }

  const int col = lane & 31;
  const int rhi = (lane >> 5) * 4;
  #pragma unroll
  for (int ni = 0; ni < 2; ++ni) {
    const int gn = n0 + wn + ni * 32 + col;
    #pragma unroll
    for (int mi = 0; mi < 2; ++mi)
      #pragma unroll
      for (int reg = 0; reg < 16; ++reg) {
        const int row = (reg & 3) + 8 * (reg >> 2) + rhi;
        Z[(size_t)(m0 + wm + mi * 32 + row) * 512 + gn] =
            __float2bfloat16(acc[mi][ni][reg]);
      }
  }
}

// ---------------- yconv: Y fp32->bf16, fused v = Y·w2 row-dots -------------
// 8388608 elems = 4096 blocks * 2048. Each wave covers exactly one 512-row.
__global__ __launch_bounds__(256) void yconv(const float* __restrict__ k,
                                             const float* __restrict__ w2,
                                             bf16* __restrict__ ko,
                                             float* __restrict__ v) {
  const size_t e = ((size_t)blockIdx.x * 256 + threadIdx.x) * 8;
  const float* src = k + e;
  bf16*        dst = ko + e;
  const float* wv  = w2 + (int)(e & 511);

  float4 a = *(const float4*)src;
  float4 c = *(const float4*)(src + 4);
  bf16 t[8];
  cvt8(a, c, t);
  *(short8*)dst = *(short8*)t;

  float4 wa = *(const float4*)wv;
  float4 wb = *(const float4*)(wv + 4);
  float p = a.x * wa.x + a.y * wa.y + a.z * wa.z + a.w * wa.w +
            c.x * wb.x + c.y * wb.y + c.z * wb.z + c.w * wb.w;
  #pragma unroll
  for (int d = 1; d < 64; d <<= 1) p += __shfl_xor(p, d, 64);
  if ((threadIdx.x & 63) == 0) v[e >> 9] = p;
}

// ---------------- out = [Z·Y^T + u + v]/64, mask -> -inf -------------------
// Verbatim R0 qk_gemm (128x128 tile, 256 thr, 2048 blocks ~3/CU); epilogue +u+v.
__global__ __launch_bounds__(256) void qk_gemm(const bf16* __restrict__ Q,
                                               const bf16* __restrict__ Kp,
                                               const unsigned char* __restrict__ mask,
                                               const float* __restrict__ u,
                                               const float* __restrict__ v,
                                               float* __restrict__ out) {
  __shared__ bf16 sA[2][128 * 32];
  __shared__ bf16 sB[2][128 * 32];
  const int b = blockIdx.z;
  const bf16* A  = Q  + (size_t)b * 2048 * 512;
  const bf16* Bm = Kp + (size_t)b * 4096 * 512;
  float* ob = out + (size_t)b * 2048 * 4096;
  const unsigned char* mb = mask + (size_t)b * 4096;
  const float* ub = u + (size_t)b * 2048;
  const float* vb = v + (size_t)b * 4096;
  const int m0 = blockIdx.x * 128;
  const int n0 = blockIdx.y * 128;

  const int tid  = threadIdx.x;
  const int lane = tid & 63;
  const int w    = tid >> 6;
  const int wm   = (w >> 1) * 64;
  const int wn   = (w & 1) * 64;
  const int st_row = lane >> 2;
  const int st_col = (lane & 3) * 8;

  floatx16 acc[2][2];
  #pragma unroll
  for (int mi = 0; mi < 2; ++mi)
    #pragma unroll
    for (int ni = 0; ni < 2; ++ni)
      #pragma unroll
      for (int r = 0; r < 16; ++r)
        acc[mi][ni][r] = 0.f;

  for (int kt = 0; kt < 512; kt += 64) {
    #pragma unroll
    for (int h = 0; h < 2; ++h)
      #pragma unroll
      for (int j = 0; j < 2; ++j) {
        const int r = (w << 5) + (j << 4);
        const bf16* ga = A  + (size_t)(m0 + r + st_row) * 512 + kt + h * 32 + st_col;
        const bf16* gb = Bm + (size_t)(n0 + r + st_row) * 512 + kt + h * 32 + st_col;
        gld_lds16(ga, &sA[h][r * 32]);
        gld_lds16(gb, &sB[h][r * 32]);
      }
    __syncthreads();

    #pragma unroll
    for (int h = 0; h < 2; ++h)
      mfma_tile32(sA[h], sB[h], wm, wn, lane, acc);
    __syncthreads();
  }

  const int col = lane & 31;
  const int rhi = (lane >> 5) * 4;
  const float scale = 1.0f / 64.0f;      // 1 / (N_HEADS * sqrt(HEAD_DIM))
  #pragma unroll
  for (int ni = 0; ni < 2; ++ni) {
    const int gn = n0 + wn + ni * 32 + col;
    const bool msk = mb[gn] != 0;
    const float vc = vb[gn];
    #pragma unroll
    for (int mi = 0; mi < 2; ++mi) {
      #pragma unroll
      for (int reg = 0; reg < 16; ++reg) {
        const int row = (reg & 3) + 8 * (reg >> 2) + rhi;
        const int gm = m0 + wm + mi * 32 + row;
        ob[(size_t)gm * 4096 + gn] =
            msk ? NEG_INF : (acc[mi][ni][reg] + ub[gm] + vc) * scale;
      }
    }
  }
}

extern "C" void kernel_launch(void* const* d_in, const int* in_sizes, int n_in,
                              void* d_out, int out_size, void* d_ws, size_t ws_size,
                              hipStream_t stream) {
  const float* query = (const float*)d_in[0];
  const float* keys  = (const float*)d_in[1];
  const unsigned char* mask = (const unsigned char*)d_in[2];  // numpy bool = 1B
  const float* q_w = (const float*)d_in[3];
  const float* q_b = (const float*)d_in[4];
  const float* k_w = (const float*)d_in[5];
  const float* k_b = (const float*)d_in[6];
  float* out = (float*)d_out;

  // workspace carve, ~24.6 MiB
  char* ws = (char*)d_ws;
  bf16*  mt_bf = (bf16*)(ws);                        //   512*512 bf16
  bf16*  z_bf  = (bf16*)(ws + 524288);               //  8192*512 bf16
  bf16*  y_bf  = (bf16*)(ws + 8912896);              // 16384*512 bf16
  float* u     = (float*)(ws + 25690112);            //  8192 f32
  float* v     = (float*)(ws + 25722880);            // 16384 f32
  float* w1    = (float*)(ws + 25788416);            //   512 f32
  float* w2    = (float*)(ws + 25790464);            //   512 f32
  float* cks   = (float*)(ws + 25792512);            //     1 f32

  prep<<<80, 256, 0, stream>>>(q_w, k_w, q_b, k_b, mt_bf, w1, w2, cks);
  proj_z<<<dim3(64, 4), 256, 0, stream>>>(query, mt_bf, w1, cks, z_bf, u);
  yconv<<<4096, 256, 0, stream>>>(keys, w2, y_bf, v);
  qk_gemm<<<dim3(16, 32, 4), 256, 0, stream>>>(z_bf, y_bf, mask, u, v, out);
}

// Round 6
// 305.907 us; speedup vs baseline: 1.0283x; 1.0283x over previous
//
#include <hip/hip_runtime.h>
#include <hip/hip_bf16.h>

using bf16 = __hip_bfloat16;
typedef __attribute__((ext_vector_type(8))) short short8;     // 8 bf16 MFMA a/b frag
typedef __attribute__((ext_vector_type(16))) float floatx16;  // 32x32 MFMA c/d frag

#define NEG_INF (-__builtin_huge_valf())

// async global->LDS, 16B per lane. LDS dest is wave-uniform base + lane*16.
__device__ __forceinline__ void gld_lds16(const void* g, void* l) {
  __builtin_amdgcn_global_load_lds(
      (const __attribute__((address_space(1))) unsigned int*)g,
      (__attribute__((address_space(3))) unsigned int*)l, 16, 0, 0);
}

__device__ __forceinline__ void cvt8(const float4& a, const float4& b, bf16* t) {
  t[0] = __float2bfloat16(a.x); t[1] = __float2bfloat16(a.y);
  t[2] = __float2bfloat16(a.z); t[3] = __float2bfloat16(a.w);
  t[4] = __float2bfloat16(b.x); t[5] = __float2bfloat16(b.y);
  t[6] = __float2bfloat16(b.z); t[7] = __float2bfloat16(b.w);
}

// ---- algebra: logits = [X·M·Y^T + u·1^T + 1·v^T + c]/64,
//      M = qw^T·kw,  u = X·(qw^T kb),  v = Y·(kw^T qb),  c = qb·kb.
//
// ---- LDS tile swizzle (T2, fixes 16-way conflict measured in R5):
//   [128][32]-bf16 tile, rows 64 B = 4 chunks of 16 B.
//   physical chunk(row, c) = c ^ ((row>>1)&3).
//   Reads (rows = lane&31 within 32-row groups): each wave instruction now
//   touches all 8 bank-quads uniformly 8x  -> conflict-free (enumerated).
//   gld_lds staging: LDS dest linear, global SOURCE pre-swizzled with the
//   same involution (lane l stages logical chunk (l&3)^((l>>3)&3)).

// ---------------- prep (fused, 80 blocks)  [verified R4] -------------------
//   blocks 0-63 : Mt[n,k] = M[k,n] = sum_i qw[i,k]*kw[i,n]  (bf16, 64x64 tile)
//   blocks 64-79: w1 = qw^T·kb (8) / w2 = kw^T·qb (8); block 64 adds c = qb·kb
__global__ __launch_bounds__(256) void prep(const float* __restrict__ qw,
                                            const float* __restrict__ kw,
                                            const float* __restrict__ qb,
                                            const float* __restrict__ kb,
                                            bf16* __restrict__ mtp,
                                            float* __restrict__ w1,
                                            float* __restrict__ w2,
                                            float* __restrict__ cks) {
  __shared__ float pool[2][2][8][64];   // 8 KiB, reused by both halves
  const int bid = blockIdx.x;
  const int tid = threadIdx.x;

  if (bid < 64) {
    float (*skw)[8][64] = pool[0];      // kw[i, n0+..]
    float (*sqw)[8][64] = pool[1];      // qw[i, k0+..]
    const int n0 = (bid >> 3) * 64, k0 = (bid & 7) * 64;
    const int tr = tid >> 4, tc = tid & 15;
    const int sr = tid >> 5, sc = (tid & 31) * 2;
    float acc[4][4];
    #pragma unroll
    for (int x = 0; x < 4; ++x)
      #pragma unroll
      for (int y = 0; y < 4; ++y) acc[x][y] = 0.f;

    auto stage = [&](int buf, int i0) {
      float2 kv = *(const float2*)&kw[(size_t)(i0 + sr) * 512 + n0 + sc];
      float2 qv = *(const float2*)&qw[(size_t)(i0 + sr) * 512 + k0 + sc];
      skw[buf][sr][sc] = kv.x; skw[buf][sr][sc + 1] = kv.y;
      sqw[buf][sr][sc] = qv.x; sqw[buf][sr][sc + 1] = qv.y;
    };
    stage(0, 0);
    __syncthreads();
    for (int cb = 0; cb < 64; ++cb) {
      if (cb < 63) stage((cb + 1) & 1, (cb + 1) * 8);
      const int buf = cb & 1;
      #pragma unroll
      for (int ii = 0; ii < 8; ++ii) {
        float av[4], bv[4];
        #pragma unroll
        for (int x = 0; x < 4; ++x) av[x] = skw[buf][ii][tr * 4 + x];
        #pragma unroll
        for (int y = 0; y < 4; ++y) bv[y] = sqw[buf][ii][tc * 4 + y];
        #pragma unroll
        for (int x = 0; x < 4; ++x)
          #pragma unroll
          for (int y = 0; y < 4; ++y) acc[x][y] += av[x] * bv[y];
      }
      __syncthreads();
    }
    #pragma unroll
    for (int x = 0; x < 4; ++x)
      #pragma unroll
      for (int y = 0; y < 4; ++y)
        mtp[(size_t)(n0 + tr * 4 + x) * 512 + k0 + tc * 4 + y] =
            __float2bfloat16(acc[x][y]);
  } else {
    const int bid2 = bid - 64;          // 0..15
    const bool isW1 = bid2 < 8;
    const float* src = isW1 ? qw : kw;
    const float* vec = isW1 ? kb : qb;
    float* outp      = isW1 ? w1 : w2;
    const int j = ((bid2 & 7) << 6) | (tid & 63);
    const int q = tid >> 6;             // wave id, i-quarter
    float p = 0.f;
    #pragma unroll 8
    for (int i = q * 128; i < q * 128 + 128; ++i)
      p += src[(size_t)i * 512 + j] * vec[i];
    float* red = &pool[0][0][0][0];
    red[tid] = p;
    __syncthreads();
    if (tid < 64)
      outp[j] = red[tid] + red[tid + 64] + red[tid + 128] + red[tid + 192];
    if (bid2 == 0) {                    // block-uniform branch
      __syncthreads();
      red[tid] = qb[tid] * kb[tid] + qb[tid + 256] * kb[tid + 256];
      __syncthreads();
      for (int s = 128; s > 0; s >>= 1) {
        if (tid < s) red[tid] += red[tid + s];
        __syncthreads();
      }
      if (tid == 0) *cks = red[0];
    }
  }
}

// 32x32x16 MFMA block: wave covers 64x64 as 2x2 of 32x32 tiles.
// A/B operand: m|n = lane&31, k = (lane>>5)*8 + j
// C/D: col = lane&31, row = (reg&3) + 8*(reg>>2) + 4*(lane>>5)   [m74/m101]
// LDS tiles are chunk-swizzled (see header): phys chunk = cc ^ ((fm>>1)&3),
// cc = ks*2 + (lane>>5); row bases are multiples of 32 so swizzle is
// per-lane constant. Conflict-free (uniform 8 accesses/bank-quad).
__device__ __forceinline__ void mfma_tile32(const bf16* sAh, const bf16* sBh,
                                            int wm, int wn, int lane,
                                            floatx16 acc[2][2]) {
  const int fm = lane & 31;
  const int hi = lane >> 5;
  const int sw = (fm >> 1) & 3;
  #pragma unroll
  for (int ks = 0; ks < 2; ++ks) {
    const int ca = ((ks * 2 + hi) ^ sw) * 8;
    short8 a0 = *(const short8*)(sAh + (wm +  0 + fm) * 32 + ca);
    short8 a1 = *(const short8*)(sAh + (wm + 32 + fm) * 32 + ca);
    short8 b0 = *(const short8*)(sBh + (wn +  0 + fm) * 32 + ca);
    short8 b1 = *(const short8*)(sBh + (wn + 32 + fm) * 32 + ca);
    acc[0][0] = __builtin_amdgcn_mfma_f32_32x32x16_bf16(a0, b0, acc[0][0], 0, 0, 0);
    acc[0][1] = __builtin_amdgcn_mfma_f32_32x32x16_bf16(a0, b1, acc[0][1], 0, 0, 0);
    acc[1][0] = __builtin_amdgcn_mfma_f32_32x32x16_bf16(a1, b0, acc[1][0], 0, 0, 0);
    acc[1][1] = __builtin_amdgcn_mfma_f32_32x32x16_bf16(a1, b1, acc[1][1], 0, 0, 0);
  }
}

// ---------------- proj_z: Z_bf16 = cvt(X_f32)·Mt^T, fused u = X·w1 + c -----
__global__ __launch_bounds__(256) void proj_z(const float* __restrict__ X,
                                              const bf16* __restrict__ Mt,
                                              const float* __restrict__ w1,
                                              const float* __restrict__ cks,
                                              bf16* __restrict__ Z,
                                              float* __restrict__ u) {
  __shared__ bf16 sA[2][128 * 32];
  __shared__ bf16 sB[2][128 * 32];
  const int m0 = blockIdx.x * 128;
  const int n0 = blockIdx.y * 128;
  const bool doU = (blockIdx.y == 0);

  const int tid  = threadIdx.x;
  const int lane = tid & 63;
  const int w    = tid >> 6;
  const int wm   = (w >> 1) * 64;
  const int wn   = (w & 1) * 64;
  const int st_row = lane >> 2;
  const int st_col = (lane & 3) * 8;                              // logical
  const int st_col_s = (((lane & 3) ^ ((lane >> 3) & 3))) * 8;    // swizzled

  floatx16 acc[2][2];
  #pragma unroll
  for (int mi = 0; mi < 2; ++mi)
    #pragma unroll
    for (int ni = 0; ni < 2; ++ni)
      #pragma unroll
      for (int r = 0; r < 16; ++r)
        acc[mi][ni][r] = 0.f;

  float pu[2] = {0.f, 0.f};             // u-partials for this thread's 2 rows

  for (int kt = 0; kt < 512; kt += 64) {
    // B-side: async DMA, linear LDS dest + swizzled global source
    #pragma unroll
    for (int h = 0; h < 2; ++h)
      #pragma unroll
      for (int j = 0; j < 2; ++j) {
        const int r = (w << 5) + (j << 4);
        gld_lds16(Mt + (size_t)(n0 + r + st_row) * 512 + kt + h * 32 + st_col_s,
                  &sB[h][r * 32]);
      }
    // A-side: fp32 load (logical cols), cvt, ds_write to swizzled chunk
    #pragma unroll
    for (int h = 0; h < 2; ++h)
      #pragma unroll
      for (int j = 0; j < 2; ++j) {
        const int row = (w << 5) + (j << 4) + st_row;
        const float* ga = X + (size_t)(m0 + row) * 512 + kt + h * 32 + st_col;
        float4 a0 = *(const float4*)ga;
        float4 a1 = *(const float4*)(ga + 4);
        bf16 ta[8];
        cvt8(a0, a1, ta);
        *(short8*)(&sA[h][row * 32 + st_col_s]) = *(short8*)ta;
        if (doU) {
          const float* wv = w1 + kt + h * 32 + st_col;
          float4 wa = *(const float4*)wv;
          float4 wb = *(const float4*)(wv + 4);
          pu[j] += a0.x * wa.x + a0.y * wa.y + a0.z * wa.z + a0.w * wa.w +
                   a1.x * wb.x + a1.y * wb.y + a1.z * wb.z + a1.w * wb.w;
        }
      }
    __syncthreads();

    #pragma unroll
    for (int h = 0; h < 2; ++h)
      mfma_tile32(sA[h], sB[h], wm, wn, lane, acc);
    __syncthreads();
  }

  if (doU) {
    const float c = *cks;
    #pragma unroll
    for (int j = 0; j < 2; ++j) {
      float p = pu[j];
      p += __shfl_xor(p, 1, 64);
      p += __shfl_xor(p, 2, 64);
      if ((lane & 3) == 0)
        u[m0 + (w << 5) + (j << 4) + st_row] = p + c;
    }
  }

  const int col = lane & 31;
  const int rhi = (lane >> 5) * 4;
  #pragma unroll
  for (int ni = 0; ni < 2; ++ni) {
    const int gn = n0 + wn + ni * 32 + col;
    #pragma unroll
    for (int mi = 0; mi < 2; ++mi)
      #pragma unroll
      for (int reg = 0; reg < 16; ++reg) {
        const int row = (reg & 3) + 8 * (reg >> 2) + rhi;
        Z[(size_t)(m0 + wm + mi * 32 + row) * 512 + gn] =
            __float2bfloat16(acc[mi][ni][reg]);
      }
  }
}

// ---------------- yconv: Y fp32->bf16, fused v = Y·w2 row-dots -------------
// 8388608 elems = 4096 blocks * 2048. Each wave covers exactly one 512-row.
__global__ __launch_bounds__(256) void yconv(const float* __restrict__ k,
                                             const float* __restrict__ w2,
                                             bf16* __restrict__ ko,
                                             float* __restrict__ v) {
  const size_t e = ((size_t)blockIdx.x * 256 + threadIdx.x) * 8;
  const float* src = k + e;
  bf16*        dst = ko + e;
  const float* wv  = w2 + (int)(e & 511);

  float4 a = *(const float4*)src;
  float4 c = *(const float4*)(src + 4);
  bf16 t[8];
  cvt8(a, c, t);
  *(short8*)dst = *(short8*)t;

  float4 wa = *(const float4*)wv;
  float4 wb = *(const float4*)(wv + 4);
  float p = a.x * wa.x + a.y * wa.y + a.z * wa.z + a.w * wa.w +
            c.x * wb.x + c.y * wb.y + c.z * wb.z + c.w * wb.w;
  #pragma unroll
  for (int d = 1; d < 64; d <<= 1) p += __shfl_xor(p, d, 64);
  if ((threadIdx.x & 63) == 0) v[e >> 9] = p;
}

// ---------------- out = [Z·Y^T + u + v]/64, mask -> -inf -------------------
// R0 qk_gemm structure (128x128 tile, 256 thr, 2048 blocks ~3/CU) + swizzle.
__global__ __launch_bounds__(256) void qk_gemm(const bf16* __restrict__ Q,
                                               const bf16* __restrict__ Kp,
                                               const unsigned char* __restrict__ mask,
                                               const float* __restrict__ u,
                                               const float* __restrict__ v,
                                               float* __restrict__ out) {
  __shared__ bf16 sA[2][128 * 32];
  __shared__ bf16 sB[2][128 * 32];
  const int b = blockIdx.z;
  const bf16* A  = Q  + (size_t)b * 2048 * 512;
  const bf16* Bm = Kp + (size_t)b * 4096 * 512;
  float* ob = out + (size_t)b * 2048 * 4096;
  const unsigned char* mb = mask + (size_t)b * 4096;
  const float* ub = u + (size_t)b * 2048;
  const float* vb = v + (size_t)b * 4096;
  const int m0 = blockIdx.x * 128;
  const int n0 = blockIdx.y * 128;

  const int tid  = threadIdx.x;
  const int lane = tid & 63;
  const int w    = tid >> 6;
  const int wm   = (w >> 1) * 64;
  const int wn   = (w & 1) * 64;
  const int st_row = lane >> 2;
  const int st_col_s = (((lane & 3) ^ ((lane >> 3) & 3))) * 8;    // swizzled

  floatx16 acc[2][2];
  #pragma unroll
  for (int mi = 0; mi < 2; ++mi)
    #pragma unroll
    for (int ni = 0; ni < 2; ++ni)
      #pragma unroll
      for (int r = 0; r < 16; ++r)
        acc[mi][ni][r] = 0.f;

  for (int kt = 0; kt < 512; kt += 64) {
    #pragma unroll
    for (int h = 0; h < 2; ++h)
      #pragma unroll
      for (int j = 0; j < 2; ++j) {
        const int r = (w << 5) + (j << 4);
        const bf16* ga = A  + (size_t)(m0 + r + st_row) * 512 + kt + h * 32 + st_col_s;
        const bf16* gb = Bm + (size_t)(n0 + r + st_row) * 512 + kt + h * 32 + st_col_s;
        gld_lds16(ga, &sA[h][r * 32]);
        gld_lds16(gb, &sB[h][r * 32]);
      }
    __syncthreads();

    #pragma unroll
    for (int h = 0; h < 2; ++h)
      mfma_tile32(sA[h], sB[h], wm, wn, lane, acc);
    __syncthreads();
  }

  const int col = lane & 31;
  const int rhi = (lane >> 5) * 4;
  const float scale = 1.0f / 64.0f;      // 1 / (N_HEADS * sqrt(HEAD_DIM))
  #pragma unroll
  for (int ni = 0; ni < 2; ++ni) {
    const int gn = n0 + wn + ni * 32 + col;
    const bool msk = mb[gn] != 0;
    const float vc = vb[gn];
    #pragma unroll
    for (int mi = 0; mi < 2; ++mi) {
      #pragma unroll
      for (int reg = 0; reg < 16; ++reg) {
        const int row = (reg & 3) + 8 * (reg >> 2) + rhi;
        const int gm = m0 + wm + mi * 32 + row;
        ob[(size_t)gm * 4096 + gn] =
            msk ? NEG_INF : (acc[mi][ni][reg] + ub[gm] + vc) * scale;
      }
    }
  }
}

extern "C" void kernel_launch(void* const* d_in, const int* in_sizes, int n_in,
                              void* d_out, int out_size, void* d_ws, size_t ws_size,
                              hipStream_t stream) {
  const float* query = (const float*)d_in[0];
  const float* keys  = (const float*)d_in[1];
  const unsigned char* mask = (const unsigned char*)d_in[2];  // numpy bool = 1B
  const float* q_w = (const float*)d_in[3];
  const float* q_b = (const float*)d_in[4];
  const float* k_w = (const float*)d_in[5];
  const float* k_b = (const float*)d_in[6];
  float* out = (float*)d_out;

  // workspace carve, ~24.6 MiB
  char* ws = (char*)d_ws;
  bf16*  mt_bf = (bf16*)(ws);                        //   512*512 bf16
  bf16*  z_bf  = (bf16*)(ws + 524288);               //  8192*512 bf16
  bf16*  y_bf  = (bf16*)(ws + 8912896);              // 16384*512 bf16
  float* u     = (float*)(ws + 25690112);            //  8192 f32
  float* v     = (float*)(ws + 25722880);            // 16384 f32
  float* w1    = (float*)(ws + 25788416);            //   512 f32
  float* w2    = (float*)(ws + 25790464);            //   512 f32
  float* cks   = (float*)(ws + 25792512);            //     1 f32

  prep<<<80, 256, 0, stream>>>(q_w, k_w, q_b, k_b, mt_bf, w1, w2, cks);
  proj_z<<<dim3(64, 4), 256, 0, stream>>>(query, mt_bf, w1, cks, z_bf, u);
  yconv<<<4096, 256, 0, stream>>>(keys, w2, y_bf, v);
  qk_gemm<<<dim3(16, 32, 4), 256, 0, stream>>>(z_bf, y_bf, mask, u, v, out);
}